// Round 1
// baseline (295.790 us; speedup 1.0000x reference)
//
#include <hip/hip_runtime.h>
#include <stdint.h>

// MultiHeadedAttention: B=2,S=2048,D=1024,H=16,DK=64
// Pipeline: f32->f16 cvt; QKV proj GEMMs (MFMA f16); flash attention with
// rel_pos_bias + bool mask; output proj GEMM -> f32.

typedef _Float16 f16;
typedef _Float16 f16x8 __attribute__((ext_vector_type(8)));
typedef _Float16 f16x4 __attribute__((ext_vector_type(4)));
typedef float f32x4 __attribute__((ext_vector_type(4)));

#define LOG2E 1.44269504088896340736f

__device__ __forceinline__ void gload16(const void* g, void* l) {
  __builtin_amdgcn_global_load_lds(
      (const __attribute__((address_space(1))) unsigned int*)g,
      (__attribute__((address_space(3))) unsigned int*)l, 16, 0, 0);
}

// ---------------- f32 -> f16 conversion (4 elems/thread, exact grid) ------
__global__ __launch_bounds__(256) void cvt_f32_f16(const float* __restrict__ in,
                                                   f16* __restrict__ out, int n4) {
  const int i = blockIdx.x * 256 + threadIdx.x;
  if (i >= n4) return;
  const float4 v = ((const float4*)in)[i];
  f16x4 o = {(f16)v.x, (f16)v.y, (f16)v.z, (f16)v.w};
  ((f16x4*)out)[i] = o;
}

// ---------------- mask dtype classify + canonicalize to u8 ----------------
// If mask arrives as 4-byte ints (or f32 0/1.0), bytes at offset%4!=0 of the
// first 8 KiB are all zero (value 1 -> bytes {01,00,00,00}); random bool8
// bytes make that impossible (p ~ 2^-6000). f32 1.0 has bytes {00,00,80,3f}
// (>1) -> also classified as 4-byte via the v>1 check.
__global__ void mask_detect(const uint8_t* __restrict__ m, int* __restrict__ flag) {
  __shared__ int s_off, s_weird;
  const int t = threadIdx.x;
  if (t == 0) { s_off = 0; s_weird = 0; }
  __syncthreads();
  int f_off = 0, f_weird = 0;
  for (int i = t; i < 8192; i += 256) {
    const uint8_t v = m[i];
    if ((i & 3) && v) f_off = 1;
    if (v > 1) f_weird = 1;
  }
  if (f_off) atomicOr(&s_off, 1);
  if (f_weird) atomicOr(&s_weird, 1);
  __syncthreads();
  if (t == 0) *flag = (s_off && !s_weird) ? 1 : 0;  // 1 => byte-sized bool
}

__global__ __launch_bounds__(256) void mask_canon(const uint8_t* __restrict__ m,
                                                  uint8_t* __restrict__ out,
                                                  const int* __restrict__ flag) {
  const int i = (blockIdx.x * 256 + threadIdx.x) * 4;  // grid covers 8388608
  uchar4 o;
  if (*flag) {
    const uchar4 v = *(const uchar4*)(m + i);
    o = make_uchar4(v.x != 0, v.y != 0, v.z != 0, v.w != 0);
  } else {
    const int4 v = *(const int4*)((const int*)m + i);
    o = make_uchar4(v.x != 0, v.y != 0, v.z != 0, v.w != 0);
  }
  *(uchar4*)(out + i) = o;
}

// ---------------- GEMM: C[m,n] = sum_k A[m,k]*B[n,k] + bias[n] ------------
// M=4096 (b*2048+s), N=1024, K=1024. 128x64 tile, 4 waves (32 rows each),
// 16x16x32 f16 MFMA, double-buffered LDS staged via global_load_lds(16B).
// MODE 0: f16 out [B,H,S,DK]   (Q,K projections)
// MODE 1: f16 out [B,H,DK,S]   (V projection, transposed for PV B-frags)
// MODE 2: f32 out [M,N]        (final output projection)
template <int MODE>
__global__ __launch_bounds__(256, 2) void gemm_bt(const f16* __restrict__ A,
                                                  const f16* __restrict__ Bw,
                                                  const float* __restrict__ bias,
                                                  void* __restrict__ outp) {
  constexpr int K = 1024;
  const int t = threadIdx.x;
  const int w = t >> 6, lane = t & 63, l15 = lane & 15, l4 = lane >> 4;
  const int bm = (int)(blockIdx.x >> 4) * 128;
  const int bn = (int)(blockIdx.x & 15) * 64;

  __shared__ f16 As[2][128 * 32];
  __shared__ f16 Bs[2][64 * 32];

  // staging sources: thread t covers tile bytes t*16 (+4096 for 2nd A call)
  const f16* a0 = A + (size_t)(bm + (t >> 2)) * K + (t & 3) * 8;
  const f16* a1 = a0 + (size_t)64 * K;
  const f16* b0 = Bw + (size_t)(bn + (t >> 2)) * K + (t & 3) * 8;

  f32x4 acc[2][4];
#pragma unroll
  for (int m = 0; m < 2; ++m)
#pragma unroll
    for (int n = 0; n < 4; ++n) acc[m][n] = (f32x4){0.f, 0.f, 0.f, 0.f};

#define STAGE_G(buf, k0)                          \
  do {                                            \
    gload16(a0 + (k0), &As[buf][w * 512]);        \
    gload16(a1 + (k0), &As[buf][2048 + w * 512]); \
    gload16(b0 + (k0), &Bs[buf][w * 512]);        \
  } while (0)

  STAGE_G(0, 0);
  __syncthreads();
  int cur = 0;
#pragma unroll 1
  for (int kt = 0; kt < 32; ++kt) {
    if (kt < 31) STAGE_G(cur ^ 1, (kt + 1) * 32);
    const f16* ap = &As[cur][(w * 32 + l15) * 32 + l4 * 8];
    const f16* bp = &Bs[cur][l15 * 32 + l4 * 8];
    f16x8 af[2], bfr[4];
#pragma unroll
    for (int m = 0; m < 2; ++m) af[m] = *(const f16x8*)(ap + m * 512);
#pragma unroll
    for (int n = 0; n < 4; ++n) bfr[n] = *(const f16x8*)(bp + n * 512);
#pragma unroll
    for (int m = 0; m < 2; ++m)
#pragma unroll
      for (int n = 0; n < 4; ++n)
        acc[m][n] = __builtin_amdgcn_mfma_f32_16x16x32_f16(af[m], bfr[n], acc[m][n], 0, 0, 0);
    __syncthreads();  // drains vmcnt (next tile staged) + lgkm (reads done)
    cur ^= 1;
  }
#undef STAGE_G

  // epilogue: C/D layout col=lane&15, row=(lane>>4)*4+reg  [m89/m91 verified]
#pragma unroll
  for (int m = 0; m < 2; ++m) {
    const int r0 = bm + w * 32 + m * 16 + (l4 << 2);
#pragma unroll
    for (int n = 0; n < 4; ++n) {
      const int c = bn + n * 16 + l15;
      const float bv = bias[c];
#pragma unroll
      for (int j = 0; j < 4; ++j) {
        const int r = r0 + j;
        const float v = acc[m][n][j] + bv;
        if (MODE == 0) {
          const int b_ = r >> 11, s = r & 2047, h_ = c >> 6, dk = c & 63;
          ((f16*)outp)[(((size_t)b_ * 16 + h_) * 2048 + s) * 64 + dk] = (f16)v;
        } else if (MODE == 1) {
          const int b_ = r >> 11, s = r & 2047, h_ = c >> 6, dk = c & 63;
          ((f16*)outp)[(((size_t)b_ * 16 + h_) * 64 + dk) * 2048 + s] = (f16)v;
        } else {
          ((float*)outp)[(size_t)r * 1024 + c] = v;
        }
      }
    }
  }
}

// ---------------- flash attention -----------------------------------------
// 512 blocks: bid -> (qt 0..15, b 0..1, h 0..15), h outermost (bias L3 reuse).
// 4 waves x 32 q-rows; kv tiles of 64. K/Vt staged with XOR-swizzled source
// (rule #21): LDS row pitch 128B would be a 16-way conflict on ds_read_b128.
__device__ __forceinline__ const f16x8* swzr(const f16* base, int row, int bytecol) {
  return (const f16x8*)((const char*)base + row * 128 + (bytecol ^ ((row & 7) << 4)));
}

__global__ __launch_bounds__(256, 2) void attn_fwd(
    const f16* __restrict__ Qp, const f16* __restrict__ Kp,
    const f16* __restrict__ Vt, const float* __restrict__ bias,
    const uint8_t* __restrict__ mask, f16* __restrict__ X) {
  constexpr int S = 2048;
  const int bid = blockIdx.x;
  const int qt = bid & 15, b = (bid >> 4) & 1, h = bid >> 5;
  const int t = threadIdx.x, w = t >> 6, lane = t & 63;
  const int l15 = lane & 15, l4 = lane >> 4;
  const int q0 = qt * 128 + w * 32;

  const f16* Qbh = Qp + (size_t)(b * 16 + h) * S * 64;
  const f16* Kbh = Kp + (size_t)(b * 16 + h) * S * 64;
  const f16* Vbh = Vt + (size_t)(b * 16 + h) * 64 * S;
  const float* biash = bias + (size_t)h * S * S;
  const uint8_t* maskb = mask + (size_t)b * S * S;

  __shared__ f16 Ks[64 * 64];   // [kv][dk], swizzled
  __shared__ f16 Vs[64 * 64];   // [dk][kv], swizzled
  __shared__ f16 Ps[4][32 * 64];  // per-wave P, swizzled

  // Q fragments in registers: row = l&15, k = 8*(l>>4)+i (contiguous)
  f16x8 qf[2][2];
#pragma unroll
  for (int m = 0; m < 2; ++m)
#pragma unroll
    for (int ks = 0; ks < 2; ++ks)
      qf[m][ks] = *(const f16x8*)(Qbh + (size_t)(q0 + m * 16 + l15) * 64 + ks * 32 + l4 * 8);

  f32x4 oacc[2][4];
#pragma unroll
  for (int m = 0; m < 2; ++m)
#pragma unroll
    for (int n = 0; n < 4; ++n) oacc[m][n] = (f32x4){0.f, 0.f, 0.f, 0.f};
  float mrow[2][4], lrow[2][4];
#pragma unroll
  for (int m = 0; m < 2; ++m)
#pragma unroll
    for (int j = 0; j < 4; ++j) { mrow[m][j] = -3e38f; lrow[m][j] = 0.f; }

  // staging: thread t -> row t/8, source col pre-swizzled (inverse of read swz)
  const int srow = t >> 3;
  const int scol = (((t & 7) ^ (srow & 7)) << 3);

#pragma unroll 1
  for (int kt = 0; kt < 32; ++kt) {
    const int k0 = kt * 64;
    __syncthreads();  // all waves done reading previous K/V tile
    gload16(Kbh + (size_t)(k0 + srow) * 64 + scol, &Ks[w * 512]);
    gload16(Kbh + (size_t)(k0 + 32 + srow) * 64 + scol, &Ks[2048 + w * 512]);
    gload16(Vbh + (size_t)srow * S + k0 + scol, &Vs[w * 512]);
    gload16(Vbh + (size_t)(32 + srow) * S + k0 + scol, &Vs[2048 + w * 512]);
    __syncthreads();  // vmcnt(0): tiles ready

    // ---- scores = Q.K^T ----
    f32x4 sacc[2][4];
#pragma unroll
    for (int m = 0; m < 2; ++m)
#pragma unroll
      for (int n = 0; n < 4; ++n) sacc[m][n] = (f32x4){0.f, 0.f, 0.f, 0.f};
    f16x8 kf[4][2];
#pragma unroll
    for (int n = 0; n < 4; ++n)
#pragma unroll
      for (int ks = 0; ks < 2; ++ks)
        kf[n][ks] = *swzr(Ks, n * 16 + l15, ks * 64 + l4 * 16);
#pragma unroll
    for (int m = 0; m < 2; ++m)
#pragma unroll
      for (int n = 0; n < 4; ++n)
#pragma unroll
        for (int ks = 0; ks < 2; ++ks)
          sacc[m][n] = __builtin_amdgcn_mfma_f32_16x16x32_f16(qf[m][ks], kf[n][ks], sacc[m][n], 0, 0, 0);

    // ---- scale + bias + mask; tile row-max ----
    float p[2][4][4];
    float tmax[2][4];
#pragma unroll
    for (int m = 0; m < 2; ++m)
#pragma unroll
      for (int j = 0; j < 4; ++j) tmax[m][j] = -3e38f;
#pragma unroll
    for (int m = 0; m < 2; ++m) {
#pragma unroll
      for (int j = 0; j < 4; ++j) {
        const int qrow = q0 + m * 16 + l4 * 4 + j;
        const float* brow = biash + (size_t)qrow * S + k0;
        const uint8_t* mrw = maskb + (size_t)qrow * S + k0;
#pragma unroll
        for (int n = 0; n < 4; ++n) {
          const int kc = n * 16 + l15;
          float s = sacc[m][n][j] * 0.125f + brow[kc];
          s = mrw[kc] ? -1e9f : s;
          p[m][n][j] = s;
          tmax[m][j] = fmaxf(tmax[m][j], s);
        }
      }
    }
    // row reduce across the 16 lanes holding this row's columns
#pragma unroll
    for (int m = 0; m < 2; ++m)
#pragma unroll
      for (int j = 0; j < 4; ++j) {
        float v = tmax[m][j];
        v = fmaxf(v, __shfl_xor(v, 1));
        v = fmaxf(v, __shfl_xor(v, 2));
        v = fmaxf(v, __shfl_xor(v, 4));
        v = fmaxf(v, __shfl_xor(v, 8));
        tmax[m][j] = v;
      }

    // ---- online softmax update; write P (f16) to per-wave LDS ----
#pragma unroll
    for (int m = 0; m < 2; ++m) {
#pragma unroll
      for (int j = 0; j < 4; ++j) {
        const float mnew = fmaxf(mrow[m][j], tmax[m][j]);
        const float alpha = __builtin_exp2f((mrow[m][j] - mnew) * LOG2E);
        mrow[m][j] = mnew;
        lrow[m][j] *= alpha;
#pragma unroll
        for (int n = 0; n < 4; ++n) oacc[m][n][j] *= alpha;
        float lsum = 0.f;
        const int prow = m * 16 + l4 * 4 + j;
#pragma unroll
        for (int n = 0; n < 4; ++n) {
          const float e = __builtin_exp2f((p[m][n][j] - mnew) * LOG2E);
          lsum += e;
          const int bc = (n * 16 + l15) * 2;
          *(f16*)((char*)&Ps[w][0] + prow * 128 + (bc ^ ((prow & 7) << 4))) = (f16)e;
        }
        lsum += __shfl_xor(lsum, 1);
        lsum += __shfl_xor(lsum, 2);
        lsum += __shfl_xor(lsum, 4);
        lsum += __shfl_xor(lsum, 8);
        lrow[m][j] += lsum;
      }
    }

    // ---- O += P.V ----
    f16x8 pf[2][2];
#pragma unroll
    for (int m = 0; m < 2; ++m)
#pragma unroll
      for (int ks = 0; ks < 2; ++ks)
        pf[m][ks] = *swzr(&Ps[w][0], m * 16 + l15, ks * 64 + l4 * 16);
#pragma unroll
    for (int ks = 0; ks < 2; ++ks)
#pragma unroll
      for (int n = 0; n < 4; ++n) {
        const f16x8 vf = *swzr(Vs, n * 16 + l15, ks * 64 + l4 * 16);
#pragma unroll
        for (int m = 0; m < 2; ++m)
          oacc[m][n] = __builtin_amdgcn_mfma_f32_16x16x32_f16(pf[m][ks], vf, oacc[m][n], 0, 0, 0);
      }
  }

  // ---- normalize and store X[b,s,h*64+dk] (f16) ----
#pragma unroll
  for (int m = 0; m < 2; ++m) {
#pragma unroll
    for (int j = 0; j < 4; ++j) {
      const float inv = 1.0f / lrow[m][j];
      const int qrow = q0 + m * 16 + l4 * 4 + j;
#pragma unroll
      for (int n = 0; n < 4; ++n) {
        const int dk = n * 16 + l15;
        X[((size_t)b * 2048 + qrow) * 1024 + h * 64 + dk] = (f16)(oacc[m][n][j] * inv);
      }
    }
  }
}

// ---------------- host ------------------------------------------------------
extern "C" void kernel_launch(void* const* d_in, const int* in_sizes, int n_in,
                              void* d_out, int out_size, void* d_ws, size_t ws_size,
                              hipStream_t stream) {
  const float* query = (const float*)d_in[0];
  const float* key_ = (const float*)d_in[1];
  const float* value = (const float*)d_in[2];
  const uint8_t* mask = (const uint8_t*)d_in[3];
  const float* bias = (const float*)d_in[4];
  const float* Wq = (const float*)d_in[5];
  const float* bq = (const float*)d_in[6];
  const float* Wk = (const float*)d_in[7];
  const float* bk = (const float*)d_in[8];
  const float* Wv = (const float*)d_in[9];
  const float* bv = (const float*)d_in[10];
  const float* Wo = (const float*)d_in[11];
  const float* bo = (const float*)d_in[12];

  // workspace layout (~75.5 MB)
  char* p = (char*)d_ws;
  f16* qh = (f16*)p; p += (size_t)4194304 * 2;
  f16* kh = (f16*)p; p += (size_t)4194304 * 2;
  f16* vh = (f16*)p; p += (size_t)4194304 * 2;
  f16* wqh = (f16*)p; p += (size_t)1048576 * 2;
  f16* wkh = (f16*)p; p += (size_t)1048576 * 2;
  f16* wvh = (f16*)p; p += (size_t)1048576 * 2;
  f16* woh = (f16*)p; p += (size_t)1048576 * 2;
  f16* Qp = (f16*)p; p += (size_t)4194304 * 2;
  f16* Kp = (f16*)p; p += (size_t)4194304 * 2;
  f16* Vt = (f16*)p; p += (size_t)4194304 * 2;
  f16* Xh = (f16*)p; p += (size_t)4194304 * 2;
  uint8_t* m8 = (uint8_t*)p; p += (size_t)8388608;
  int* flag = (int*)p; p += 256;
  if (ws_size < (size_t)(p - (char*)d_ws)) return;  // insufficient scratch

  mask_detect<<<1, 256, 0, stream>>>(mask, flag);
  mask_canon<<<8192, 256, 0, stream>>>(mask, m8, flag);

  cvt_f32_f16<<<4096, 256, 0, stream>>>(query, qh, 1048576);
  cvt_f32_f16<<<4096, 256, 0, stream>>>(key_, kh, 1048576);
  cvt_f32_f16<<<4096, 256, 0, stream>>>(value, vh, 1048576);
  cvt_f32_f16<<<1024, 256, 0, stream>>>(Wq, wqh, 262144);
  cvt_f32_f16<<<1024, 256, 0, stream>>>(Wk, wkh, 262144);
  cvt_f32_f16<<<1024, 256, 0, stream>>>(Wv, wvh, 262144);
  cvt_f32_f16<<<1024, 256, 0, stream>>>(Wo, woh, 262144);

  gemm_bt<0><<<512, 256, 0, stream>>>(qh, wqh, bq, Qp);
  gemm_bt<0><<<512, 256, 0, stream>>>(kh, wkh, bk, Kp);
  gemm_bt<1><<<512, 256, 0, stream>>>(vh, wvh, bv, Vt);

  attn_fwd<<<512, 256, 0, stream>>>(Qp, Kp, Vt, bias, m8, Xh);

  gemm_bt<2><<<512, 256, 0, stream>>>(Xh, woh, bo, d_out);
}